// Round 1
// baseline (818.283 us; speedup 1.0000x reference)
//
#include <hip/hip_runtime.h>
#include <math.h>

#define BATCH  32
#define NPTS   8192
#define NGROUP 512
#define MSIZE  32

#define FPS_THREADS 512
#define SXYZ_FLOATS (NPTS * 3)
#define DYN_LDS_BYTES (SXYZ_FLOATS * 4)   // 98304 B, used by BOTH kernels

#define KNN_THREADS 512
#define KNN_SEGS    8     // blocks per batch
#define KNN_GPW     8     // groups per wave (8 segs * 8 waves * 8 = 512 groups)

typedef float v2f __attribute__((ext_vector_type(2)));

// ---- DPP helpers (CTRL compile-time const) --------------------------------
// f32 max: bound_ctrl=true -> masked-off lanes read 0; fmax(x,0)=x for x>=0.
template<int CTRL>
__device__ __forceinline__ float dpp_max_f32(float x) {
    int o = __builtin_amdgcn_update_dpp(0, __float_as_int(x), CTRL, 0xF, 0xF, true);
    float f = __int_as_float(o);
    return x > f ? x : f;
}
// u32 min: bound_ctrl=true -> masked lanes read 0 (poisons that lane's value),
// but for the bcast15/bcast31 tail the lane-63 result only ever consumes valid
// lanes (15/31/47 row minima), so readlane(.,63) is the exact global min.
template<int CTRL>
__device__ __forceinline__ unsigned dpp_min_u32_full(unsigned x) {
    unsigned o = (unsigned)__builtin_amdgcn_update_dpp(0, (int)x, CTRL, 0xF, 0xF, true);
    return o < x ? o : x;
}

__device__ __forceinline__ unsigned long long u64max(unsigned long long a,
                                                     unsigned long long b) {
    return a > b ? a : b;
}

// ---------------------------------------------------------------------------
// FPS: one block/batch, 512 threads (8 waves), 16 pts/thread as v2f pairs
// (packed f32 math, per-element bit-exact numpy order, contract off).
// Ownership CONTIGUOUS: thread t owns [16t,16t+16).
// Cross-wave reduce: per-wave key SLOTS (plain ds_write_b64 by lane 63,
// double-buffered by step parity) + post-barrier 8-way u64 max tree.
// Replaces the old same-address ds atomicMax (8 serialized atomics) and the
// dependent gkey->fi->sxyz chain's first hop. Double-buffer safety: a wave
// writes slot set (g&1); a reader of set (g&1) sits between barrier(g-1) and
// barrier(g); the next writer of that set is after barrier(g+1) -> no race
// with exactly one barrier per step.
// Tie semantics unchanged: key = (wmaxbits<<32)|~widx, max-reduce ==
// first-occurrence argmax (dists >= 0 so float-bit compare is order-exact).
// ---------------------------------------------------------------------------
__global__ __launch_bounds__(FPS_THREADS, 2)
void fps_kernel(const float* __restrict__ xyz,
                float* __restrict__ out_center,
                float* __restrict__ out_fps)
{
#pragma clang fp contract(off)
    extern __shared__ float sxyz[];                        // [24576]
    __shared__ unsigned long long s_key[2][8];

    const int b    = blockIdx.x;
    const int t    = threadIdx.x;
    const int lane = t & 63;
    const int wid  = t >> 6;
    const float* bp = xyz + (size_t)b * NPTS * 3;
    const float4* bp4 = reinterpret_cast<const float4*>(bp);
    float4* s4 = reinterpret_cast<float4*>(sxyz);

    // contiguous ownership: thread t owns points 16t..16t+15 (12 float4).
    v2f px2[8], py2[8], pz2[8], dist2[8];
    {
        float f[48];
        #pragma unroll
        for (int q = 0; q < 12; ++q) {
            float4 v = bp4[t * 12 + q];
            s4[t * 12 + q] = v;
            f[q*4+0] = v.x; f[q*4+1] = v.y; f[q*4+2] = v.z; f[q*4+3] = v.w;
        }
        #pragma unroll
        for (int j = 0; j < 8; ++j) {
            px2[j] = (v2f){f[6*j+0], f[6*j+3]};
            py2[j] = (v2f){f[6*j+1], f[6*j+4]};
            pz2[j] = (v2f){f[6*j+2], f[6*j+5]};
            dist2[j] = (v2f){INFINITY, INFINITY};
        }
    }
    __syncthreads();   // sxyz visible

    if (t == 0) {
        out_fps[(size_t)b * NGROUP] = 0.0f;
        out_center[(size_t)(b * NGROUP) * 3 + 0] = sxyz[0];
        out_center[(size_t)(b * NGROUP) * 3 + 1] = sxyz[1];
        out_center[(size_t)(b * NGROUP) * 3 + 2] = sxyz[2];
    }

    int last = 0;
    for (int g = 1; g < NGROUP; ++g) {
        float lx = sxyz[last*3 + 0];     // broadcast LDS reads
        float ly = sxyz[last*3 + 1];
        float lz = sxyz[last*3 + 2];

        // packed dist update: per element (dx*dx + dy*dy) + dz*dz, then min
        #pragma unroll
        for (int j = 0; j < 8; ++j) {
            v2f dx = px2[j] - lx;
            v2f dy = py2[j] - ly;
            v2f dz = pz2[j] - lz;
            v2f t1 = dx * dx;
            v2f t2 = dy * dy;
            v2f t3 = dz * dz;
            v2f s  = t1 + t2;
            v2f d  = s + t3;
            dist2[j] = __builtin_elementwise_min(dist2[j], d);
        }
        // per-thread max (exact, order-free)
        v2f mm0 = __builtin_elementwise_max(dist2[0], dist2[1]);
        v2f mm1 = __builtin_elementwise_max(dist2[2], dist2[3]);
        v2f mm2 = __builtin_elementwise_max(dist2[4], dist2[5]);
        v2f mm3 = __builtin_elementwise_max(dist2[6], dist2[7]);
        v2f mma = __builtin_elementwise_max(mm0, mm1);
        v2f mmb = __builtin_elementwise_max(mm2, mm3);
        v2f mmc = __builtin_elementwise_max(mma, mmb);
        float m_t = fmaxf(mmc.x, mmc.y);

        // wave max via DPP -> wmax (uniform)
        float m = m_t;
        m = dpp_max_f32<0xB1>(m);     // quad_perm xor1
        m = dpp_max_f32<0x4E>(m);     // quad_perm xor2
        m = dpp_max_f32<0x141>(m);    // row_half_mirror
        m = dpp_max_f32<0x140>(m);    // row_mirror
        m = dpp_max_f32<0x142>(m);    // row_bcast15
        m = dpp_max_f32<0x143>(m);    // row_bcast31
        float wmax = __int_as_float(__builtin_amdgcn_readlane(__float_as_int(m), 63));

        // lowest candidate lane (contiguous ownership => lane order = idx order)
        unsigned long long mask = __ballot(m_t == wmax);
        int l = __ffsll((long long)mask) - 1;

        // lowest j with d[j]==wmax: pair candidates + 3-level min tree
        // (dep depth ~5 vs old 16-deep select chain)
        unsigned cand[8];
        #pragma unroll
        for (int p = 0; p < 8; ++p) {
            unsigned c = 0xFFFFFFFFu;
            c = (dist2[p].y == wmax) ? (unsigned)(2*p + 1) : c;
            c = (dist2[p].x == wmax) ? (unsigned)(2*p)     : c;   // x preferred (lower j)
            cand[p] = c;
        }
        unsigned q0 = cand[0] < cand[1] ? cand[0] : cand[1];
        unsigned q1 = cand[2] < cand[3] ? cand[2] : cand[3];
        unsigned q2 = cand[4] < cand[5] ? cand[4] : cand[5];
        unsigned q3 = cand[6] < cand[7] ? cand[6] : cand[7];
        unsigned qa = q0 < q1 ? q0 : q1;
        unsigned qb = q2 < q3 ? q2 : q3;
        unsigned lj = qa < qb ? qa : qb;       // <16 on candidate lanes
        unsigned idx = ((unsigned)t << 4) | lj;
        unsigned widx = (unsigned)__builtin_amdgcn_readlane((int)idx, l);

        if (lane == 63) {
            s_key[g & 1][wid] =
                (((unsigned long long)__float_as_uint(wmax)) << 32) | (unsigned)~widx;
        }
        __syncthreads();                  // the ONE barrier

        const unsigned long long* sk = s_key[g & 1];
        unsigned long long a0 = u64max(sk[0], sk[1]);
        unsigned long long a1 = u64max(sk[2], sk[3]);
        unsigned long long a2 = u64max(sk[4], sk[5]);
        unsigned long long a3 = u64max(sk[6], sk[7]);
        unsigned long long km = u64max(u64max(a0, a1), u64max(a2, a3));
        int fi = (int)(~(unsigned)km);
        last = fi;
        if (t == 0) {
            out_fps[(size_t)b * NGROUP + g] = (float)fi;
            out_center[((size_t)(b * NGROUP + g)) * 3 + 0] = sxyz[fi*3 + 0];
            out_center[((size_t)(b * NGROUP + g)) * 3 + 1] = sxyz[fi*3 + 1];
            out_center[((size_t)(b * NGROUP + g)) * 3 + 2] = sxyz[fi*3 + 2];
        }
    }
}

// ---------------------------------------------------------------------------
// kNN, LDS-resident: 256 blocks (8/batch) x 512 threads; the whole batch
// (8192 pts) staged once per block in SoA LDS (sx/sy/sz, 96 KB), then each of
// the 8 waves processes 8 groups serially from LDS. Cuts L2 traffic 64x vs
// the old per-wave global stream (each batch was re-read 512x).
// Staging: STRIDED ownership (thread t stages pts {t, t+512, ...}) ->
//   global float3 reads coalesced (64 lanes x 12B contiguous) AND
//   ds_write_b32 addressed p = t+512s -> bank = t&31 -> conflict-free.
// Reads: float4 at byte lane*16 -> canonical conflict-free LDS pattern.
// Distance math / key truncation / insert order bit-identical to previous
// version (same v2f pairing {p0,p1},{p2,p3}, contract allowed as before).
// Reduce: 6-stage DPP u32-min + readlane(63) replaces 4 DPP + 2 shfl_xor
// (shfl = LDS-pipe round trip); exact same unique-key pop semantics.
// ---------------------------------------------------------------------------
__global__ __launch_bounds__(KNN_THREADS, 1)
void knn_kernel(const float* __restrict__ xyz,
                const float* __restrict__ center,
                float* __restrict__ out_nbhd)
{
    extern __shared__ float sm[];          // sx[8192] sy[8192] sz[8192]
    float* sx = sm;
    float* sy = sm + NPTS;
    float* sz = sm + 2 * NPTS;

    const int t    = threadIdx.x;
    const int lane = t & 63;
    const int wid  = t >> 6;
    const int b    = blockIdx.x >> 3;      // batch
    const int seg  = blockIdx.x & 7;       // segment within batch
    const float* bp = xyz + (size_t)b * NPTS * 3;

    // ---- stage SoA (strided ownership, conflict-free writes) ----
    #pragma unroll
    for (int s = 0; s < NPTS / KNN_THREADS; ++s) {
        const int p = t + KNN_THREADS * s;
        float3 v = *reinterpret_cast<const float3*>(bp + (size_t)p * 3);
        sx[p] = v.x; sy[p] = v.y; sz[p] = v.z;
    }
    __syncthreads();

    for (int k = 0; k < KNN_GPW; ++k) {
        const int gid = b * NGROUP + seg * 64 + wid * KNN_GPW + k;
        const float cx = center[(size_t)gid*3+0];
        const float cy = center[(size_t)gid*3+1];
        const float cz = center[(size_t)gid*3+2];

        unsigned kl[4];
        #pragma unroll
        for (int q = 0; q < 4; ++q) kl[q] = 0xFFFFFFFFu;

        for (int c = 0; c < 32; ++c) {
            const int p0i = c * 256 + lane * 4;
            float4 x4 = *reinterpret_cast<const float4*>(&sx[p0i]);
            float4 y4 = *reinterpret_cast<const float4*>(&sy[p0i]);
            float4 z4 = *reinterpret_cast<const float4*>(&sz[p0i]);
            v2f xA = (v2f){x4.x, x4.y}, yA = (v2f){y4.x, y4.y}, zA = (v2f){z4.x, z4.y};
            v2f xB = (v2f){x4.z, x4.w}, yB = (v2f){y4.z, y4.w}, zB = (v2f){z4.z, z4.w};
            v2f dxA = xA - cx, dyA = yA - cy, dzA = zA - cz;
            v2f dxB = xB - cx, dyB = yB - cy, dzB = zB - cz;
            v2f dA = dxA*dxA + dyA*dyA + dzA*dzA;
            v2f dB = dxB*dxB + dyB*dyB + dzB*dzB;
            float ds[4] = {dA.x, dA.y, dB.x, dB.y};
            unsigned p0 = (unsigned)p0i;
            #pragma unroll
            for (int q = 0; q < 4; ++q) {
                unsigned key = (__float_as_uint(ds[q]) & 0xFFFFE000u) | (p0 + q);
                if (key < kl[3]) {
                    kl[3] = key;
                    #pragma unroll
                    for (int w = 3; w > 0; --w) {
                        if (kl[w] < kl[w-1]) {
                            unsigned tk = kl[w]; kl[w] = kl[w-1]; kl[w-1] = tk;
                        }
                    }
                }
            }
        }

        int keep = 0;
        #pragma unroll 1
        for (int r = 0; r < MSIZE; ++r) {
            unsigned kk = kl[0];
            kk = dpp_min_u32_full<0xB1>(kk);     // xor1
            kk = dpp_min_u32_full<0x4E>(kk);     // xor2
            kk = dpp_min_u32_full<0x141>(kk);    // row_half_mirror
            kk = dpp_min_u32_full<0x140>(kk);    // row_mirror
            kk = dpp_min_u32_full<0x142>(kk);    // row_bcast15
            kk = dpp_min_u32_full<0x143>(kk);    // row_bcast31 -> lane63 = global min
            unsigned kmin = (unsigned)__builtin_amdgcn_readlane((int)kk, 63);
            if (lane == r) keep = (int)(kmin & 0x1FFFu);
            if (kl[0] == kmin) {                 // unique (idx embedded)
                kl[0] = kl[1]; kl[1] = kl[2]; kl[2] = kl[3];
                kl[3] = 0xFFFFFFFFu;
            }
        }

        if (lane < MSIZE) {
            size_t o = ((size_t)gid * MSIZE + lane) * 3;
            out_nbhd[o+0] = sx[keep] - cx;
            out_nbhd[o+1] = sy[keep] - cy;
            out_nbhd[o+2] = sz[keep] - cz;
        }
    }
}

// ---------------------------------------------------------------------------
extern "C" void kernel_launch(void* const* d_in, const int* in_sizes, int n_in,
                              void* d_out, int out_size, void* d_ws, size_t ws_size,
                              hipStream_t stream)
{
    const float* xyz = (const float*)d_in[0];
    float* out        = (float*)d_out;
    float* out_nbhd   = out;                                    // 32*512*32*3
    float* out_center = out + (size_t)BATCH*NGROUP*MSIZE*3;     // 32*512*3
    float* out_fps    = out_center + (size_t)BATCH*NGROUP*3;    // 32*512

    hipFuncSetAttribute(reinterpret_cast<const void*>(fps_kernel),
                        hipFuncAttributeMaxDynamicSharedMemorySize,
                        DYN_LDS_BYTES);
    hipFuncSetAttribute(reinterpret_cast<const void*>(knn_kernel),
                        hipFuncAttributeMaxDynamicSharedMemorySize,
                        DYN_LDS_BYTES);

    fps_kernel<<<dim3(BATCH), dim3(FPS_THREADS), DYN_LDS_BYTES, stream>>>(xyz, out_center, out_fps);
    knn_kernel<<<dim3(BATCH*KNN_SEGS), dim3(KNN_THREADS), DYN_LDS_BYTES, stream>>>(xyz, out_center, out_nbhd);
}

// Round 2
// 584.010 us; speedup vs baseline: 1.4011x; 1.4011x over previous
//
#include <hip/hip_runtime.h>
#include <math.h>

#define BATCH  32
#define NPTS   8192
#define NGROUP 512
#define MSIZE  32

#define FPS_THREADS 512
#define SXYZ_FLOATS (NPTS * 3)
#define DYN_LDS_BYTES (SXYZ_FLOATS * 4)

#define KNN_CPW 4   // centers per wave per stream (loads amortized 4x)

typedef float v2f __attribute__((ext_vector_type(2)));

// ---- DPP helpers (CTRL compile-time const) --------------------------------
// f32 max: bound_ctrl=true -> masked-off lanes read 0; fmax(x,0)=x for x>=0.
template<int CTRL>
__device__ __forceinline__ float dpp_max_f32(float x) {
    int o = __builtin_amdgcn_update_dpp(0, __float_as_int(x), CTRL, 0xF, 0xF, true);
    float f = __int_as_float(o);
    return x > f ? x : f;
}
template<int CTRL>
__device__ __forceinline__ unsigned dpp_min_u32_full(unsigned x) {
    unsigned o = (unsigned)__builtin_amdgcn_update_dpp(0, (int)x, CTRL, 0xF, 0xF, true);
    return o < x ? o : x;
}

// ---------------------------------------------------------------------------
// FPS: one block/batch, 512 threads (8 waves, 2/SIMD), 16 pts/thread as v2f
// pairs (packed f32 math, per-element bit-exact numpy order: (dx^2+dy^2)+dz^2,
// contract off). Ownership CONTIGUOUS: thread t owns [16t, 16t+16) so
// (wave,lane,j) lexicographic == global index order. Per step, ONE barrier:
//   dist update -> per-thread max m_t -> 6-stage f32 DPP -> wmax=readlane63
//   -> ballot(m_t==wmax) -> lowest candidate lane l (s_ff1)
//   -> all lanes: lj = lowest j with d[j]==wmax (cmp/sel chain); idx=(t<<4)|lj
//   -> widx = readlane(idx, l)   [wave winner, exact first-occurrence]
//   -> lane63: ds_max_u64(gkey[g%3], (wmaxbits<<32)|~widx)
//   -> barrier -> all read gkey (broadcast b64) -> fi = ~lo32.
// gkey triple-buffered; slot (g+1)%3 reset in step g (race-free: its last
// readers passed barrier(g-1) before the reset, next writers start after
// barrier(g)). Exact np.argmax first-occurrence semantics incl. ties.
// NOTE (round-1 post-mortem): do NOT replace the atomicMax with per-wave
// slots + post-barrier tree — the atomic is pre-barrier (hidden by wave
// skew); the tree sits on every wave's post-barrier critical path (+165
// cyc/step measured) and its multi-slot reads bank-conflict (73728/disp).
// ---------------------------------------------------------------------------
__global__ __launch_bounds__(FPS_THREADS, 2)
void fps_kernel(const float* __restrict__ xyz,
                float* __restrict__ out_center,
                float* __restrict__ out_fps)
{
#pragma clang fp contract(off)
    extern __shared__ float sxyz[];                        // [24576]
    __shared__ unsigned long long gkey[3];

    const int b    = blockIdx.x;
    const int t    = threadIdx.x;
    const int lane = t & 63;
    const float* bp = xyz + (size_t)b * NPTS * 3;
    const float4* bp4 = reinterpret_cast<const float4*>(bp);
    float4* s4 = reinterpret_cast<float4*>(sxyz);

    // contiguous ownership: thread t owns points 16t..16t+15 (48 floats,
    // 12 float4). Stage into LDS with the same reads.
    v2f px2[8], py2[8], pz2[8], dist2[8];
    {
        float f[48];
        #pragma unroll
        for (int q = 0; q < 12; ++q) {
            float4 v = bp4[t * 12 + q];
            s4[t * 12 + q] = v;
            f[q*4+0] = v.x; f[q*4+1] = v.y; f[q*4+2] = v.z; f[q*4+3] = v.w;
        }
        #pragma unroll
        for (int j = 0; j < 8; ++j) {
            px2[j] = (v2f){f[6*j+0], f[6*j+3]};
            py2[j] = (v2f){f[6*j+1], f[6*j+4]};
            pz2[j] = (v2f){f[6*j+2], f[6*j+5]};
            dist2[j] = (v2f){INFINITY, INFINITY};
        }
    }
    if (t == 0) { gkey[0] = 0; gkey[1] = 0; gkey[2] = 0; }
    __syncthreads();   // sxyz + gkey visible

    if (t == 0) {
        out_fps[(size_t)b * NGROUP] = 0.0f;
        out_center[(size_t)(b * NGROUP) * 3 + 0] = sxyz[0];
        out_center[(size_t)(b * NGROUP) * 3 + 1] = sxyz[1];
        out_center[(size_t)(b * NGROUP) * 3 + 2] = sxyz[2];
    }

    int last = 0;
    for (int g = 1; g < NGROUP; ++g) {
        const int slot = g % 3;
        const int nxt  = (g + 1) % 3;
        float lx = sxyz[last*3 + 0];     // broadcast LDS reads
        float ly = sxyz[last*3 + 1];
        float lz = sxyz[last*3 + 2];

        // packed dist update: per element (dx*dx + dy*dy) + dz*dz, then min
        #pragma unroll
        for (int j = 0; j < 8; ++j) {
            v2f dx = px2[j] - lx;
            v2f dy = py2[j] - ly;
            v2f dz = pz2[j] - lz;
            v2f t1 = dx * dx;
            v2f t2 = dy * dy;
            v2f t3 = dz * dz;
            v2f s  = t1 + t2;
            v2f d  = s + t3;
            dist2[j] = __builtin_elementwise_min(dist2[j], d);
        }
        // per-thread max (exact, order-free)
        v2f mm0 = __builtin_elementwise_max(dist2[0], dist2[1]);
        v2f mm1 = __builtin_elementwise_max(dist2[2], dist2[3]);
        v2f mm2 = __builtin_elementwise_max(dist2[4], dist2[5]);
        v2f mm3 = __builtin_elementwise_max(dist2[6], dist2[7]);
        v2f mma = __builtin_elementwise_max(mm0, mm1);
        v2f mmb = __builtin_elementwise_max(mm2, mm3);
        v2f mmc = __builtin_elementwise_max(mma, mmb);
        float m_t = fmaxf(mmc.x, mmc.y);

        // wave max via DPP -> wmax (uniform, sgpr)
        float m = m_t;
        m = dpp_max_f32<0xB1>(m);     // quad_perm xor1
        m = dpp_max_f32<0x4E>(m);     // quad_perm xor2
        m = dpp_max_f32<0x141>(m);    // row_half_mirror
        m = dpp_max_f32<0x140>(m);    // row_mirror
        m = dpp_max_f32<0x142>(m);    // row_bcast15
        m = dpp_max_f32<0x143>(m);    // row_bcast31
        float wmax = __int_as_float(__builtin_amdgcn_readlane(__float_as_int(m), 63));

        // lowest candidate lane (contiguous ownership => lane order = idx order)
        unsigned long long mask = __ballot(m_t == wmax);
        int l = __ffsll((long long)mask) - 1;

        // each lane: lowest j with d[j]==wmax (descending select chain)
        unsigned lj = 0;
        #pragma unroll
        for (int j = 15; j >= 0; --j) {
            float dj = (j & 1) ? dist2[j >> 1].y : dist2[j >> 1].x;
            lj = (dj == wmax) ? (unsigned)j : lj;
        }
        unsigned idx = ((unsigned)t << 4) | lj;
        unsigned widx = (unsigned)__builtin_amdgcn_readlane((int)idx, l);

        if (lane == 63) {
            unsigned long long key =
                (((unsigned long long)__float_as_uint(wmax)) << 32) | (unsigned)~widx;
            atomicMax(&gkey[slot], key);
            if (t == 63) gkey[nxt] = 0;   // reset slot for step g+1 (pre-barrier)
        }
        __syncthreads();                  // the ONE barrier

        unsigned long long kq = gkey[slot];   // broadcast b64 read
        int fi = (int)(~(unsigned)kq);
        last = fi;
        if (t == 0) {
            out_fps[(size_t)b * NGROUP + g] = (float)fi;
            out_center[((size_t)(b * NGROUP + g)) * 3 + 0] = sxyz[fi*3 + 0];
            out_center[((size_t)(b * NGROUP + g)) * 3 + 1] = sxyz[fi*3 + 1];
            out_center[((size_t)(b * NGROUP + g)) * 3 + 2] = sxyz[fi*3 + 2];
        }
    }
}

// ---------------------------------------------------------------------------
// kNN: one wave handles KNN_CPW=4 consecutive groups per stream of its batch.
// High-occupancy global streaming (xyz is 3 MB -> fully L2-resident; round-1
// showed the 96KB-LDS-resident variant is latency-bound at 2 waves/SIMD).
// The float4 loads + v2f repacks are shared across the 4 centers -> L2 read
// traffic /4 vs one-group-per-wave (1.57 GB -> 0.39 GB). Per-center distance
// math, key truncation (distbits&~0x1FFF | idx13), insert order, and the
// 32-round DPP+shfl min+pop reduce are verbatim from the verified version ->
// bit-identical results per group.
// ---------------------------------------------------------------------------
__global__ __launch_bounds__(256)
void knn_kernel(const float* __restrict__ xyz,
                const float* __restrict__ center,
                float* __restrict__ out_nbhd)
{
    const int lane = threadIdx.x & 63;
    const int wid  = threadIdx.x >> 6;
    const int gid0 = blockIdx.x * (4 * KNN_CPW) + wid * KNN_CPW; // 4 consecutive gids
    const int b    = gid0 >> 9;
    const float* bp = xyz + (size_t)b * NPTS * 3;
    const float4* bp4 = reinterpret_cast<const float4*>(bp);

    float cx[KNN_CPW], cy[KNN_CPW], cz[KNN_CPW];
    #pragma unroll
    for (int ci = 0; ci < KNN_CPW; ++ci) {
        cx[ci] = center[(size_t)(gid0 + ci)*3 + 0];
        cy[ci] = center[(size_t)(gid0 + ci)*3 + 1];
        cz[ci] = center[(size_t)(gid0 + ci)*3 + 2];
    }

    unsigned kl[KNN_CPW][4];
    #pragma unroll
    for (int ci = 0; ci < KNN_CPW; ++ci)
        #pragma unroll
        for (int k = 0; k < 4; ++k) kl[ci][k] = 0xFFFFFFFFu;

    for (int c = 0; c < 32; ++c) {
        int f4 = c * 192 + lane * 3;
        float4 a  = bp4[f4+0];
        float4 bq = bp4[f4+1];
        float4 cq = bp4[f4+2];
        unsigned p0 = (unsigned)(c * 256 + lane * 4);
        v2f xA = (v2f){a.x,  a.w},  yA = (v2f){a.y,  bq.x}, zA = (v2f){a.z,  bq.y};
        v2f xB = (v2f){bq.z, cq.y}, yB = (v2f){bq.w, cq.z}, zB = (v2f){cq.x, cq.w};
        #pragma unroll
        for (int ci = 0; ci < KNN_CPW; ++ci) {
            v2f dxA = xA - cx[ci], dyA = yA - cy[ci], dzA = zA - cz[ci];
            v2f dxB = xB - cx[ci], dyB = yB - cy[ci], dzB = zB - cz[ci];
            v2f dA = dxA*dxA + dyA*dyA + dzA*dzA;
            v2f dB = dxB*dxB + dyB*dyB + dzB*dzB;
            float ds[4] = {dA.x, dA.y, dB.x, dB.y};
            #pragma unroll
            for (int q = 0; q < 4; ++q) {
                unsigned key = (__float_as_uint(ds[q]) & 0xFFFFE000u) | (p0 + q);
                if (key < kl[ci][3]) {
                    kl[ci][3] = key;
                    #pragma unroll
                    for (int w = 3; w > 0; --w) {
                        if (kl[ci][w] < kl[ci][w-1]) {
                            unsigned tk = kl[ci][w]; kl[ci][w] = kl[ci][w-1]; kl[ci][w-1] = tk;
                        }
                    }
                }
            }
        }
    }

    #pragma unroll
    for (int ci = 0; ci < KNN_CPW; ++ci) {
        int keep = 0;
        #pragma unroll 1
        for (int r = 0; r < MSIZE; ++r) {
            unsigned k = kl[ci][0];
            k = dpp_min_u32_full<0xB1>(k);     // xor1
            k = dpp_min_u32_full<0x4E>(k);     // xor2
            k = dpp_min_u32_full<0x141>(k);    // half mirror
            k = dpp_min_u32_full<0x140>(k);    // mirror -> rows of 16 uniform
            {
                unsigned o = __shfl_xor(k, 16);
                k = o < k ? o : k;
                o = __shfl_xor(k, 32);
                k = o < k ? o : k;
            }
            if (lane == r) keep = (int)(k & 0x1FFFu);
            if (kl[ci][0] == k) {               // unique (idx embedded)
                kl[ci][0] = kl[ci][1]; kl[ci][1] = kl[ci][2]; kl[ci][2] = kl[ci][3];
                kl[ci][3] = 0xFFFFFFFFu;
            }
        }

        if (lane < MSIZE) {
            size_t o = ((size_t)(gid0 + ci) * MSIZE + lane) * 3;
            float x = bp[keep*3+0], y = bp[keep*3+1], z = bp[keep*3+2];
            out_nbhd[o+0] = x - cx[ci];
            out_nbhd[o+1] = y - cy[ci];
            out_nbhd[o+2] = z - cz[ci];
        }
    }
}

// ---------------------------------------------------------------------------
extern "C" void kernel_launch(void* const* d_in, const int* in_sizes, int n_in,
                              void* d_out, int out_size, void* d_ws, size_t ws_size,
                              hipStream_t stream)
{
    const float* xyz = (const float*)d_in[0];
    float* out        = (float*)d_out;
    float* out_nbhd   = out;                                    // 32*512*32*3
    float* out_center = out + (size_t)BATCH*NGROUP*MSIZE*3;     // 32*512*3
    float* out_fps    = out_center + (size_t)BATCH*NGROUP*3;    // 32*512

    hipFuncSetAttribute(reinterpret_cast<const void*>(fps_kernel),
                        hipFuncAttributeMaxDynamicSharedMemorySize,
                        DYN_LDS_BYTES);

    fps_kernel<<<dim3(BATCH), dim3(FPS_THREADS), DYN_LDS_BYTES, stream>>>(xyz, out_center, out_fps);
    knn_kernel<<<dim3(BATCH*NGROUP/(4*KNN_CPW)), dim3(256), 0, stream>>>(xyz, out_center, out_nbhd);
}

// Round 3
// 582.944 us; speedup vs baseline: 1.4037x; 1.0018x over previous
//
#include <hip/hip_runtime.h>
#include <math.h>

#define BATCH  32
#define NPTS   8192
#define NGROUP 512
#define MSIZE  32

#define FPS_THREADS 512
#define SXYZ_FLOATS (NPTS * 3)
#define DYN_LDS_BYTES (SXYZ_FLOATS * 4)

typedef float v2f __attribute__((ext_vector_type(2)));

// ---- DPP helpers (CTRL compile-time const) --------------------------------
// f32 max: bound_ctrl=true -> masked-off lanes read 0; fmax(x,0)=x for x>=0.
template<int CTRL>
__device__ __forceinline__ float dpp_max_f32(float x) {
    int o = __builtin_amdgcn_update_dpp(0, __float_as_int(x), CTRL, 0xF, 0xF, true);
    float f = __int_as_float(o);
    return x > f ? x : f;
}
template<int CTRL>
__device__ __forceinline__ unsigned dpp_min_u32_full(unsigned x) {
    unsigned o = (unsigned)__builtin_amdgcn_update_dpp(0, (int)x, CTRL, 0xF, 0xF, true);
    return o < x ? o : x;
}

// ---------------------------------------------------------------------------
// FPS: one block/batch, 512 threads (8 waves, 2/SIMD), 16 pts/thread as v2f
// pairs (packed f32 math, per-element bit-exact numpy order: (dx^2+dy^2)+dz^2,
// contract off). Ownership CONTIGUOUS: thread t owns [16t, 16t+16).
// Per step, ONE barrier:
//   dist update -> per-thread max m_t -> 6-stage f32 DPP -> wmax=readlane63
//   -> ballot(m_t==wmax) -> lowest candidate lane l (s_ff1)
//   -> all lanes: lj = lowest j with d[j]==wmax via pair-candidates + 3-level
//      min tree (depth ~6 vs old 16-deep cndmask chain; same semantics:
//      .x preferred over .y, min over pairs = lowest j)
//   -> widx = readlane(idx, l)   [wave winner, exact first-occurrence]
//   -> lane63: ds_max_u64(gkey[g%3], (wmaxbits<<32)|~widx)
//   -> barrier -> all read gkey (broadcast b64) -> fi = ~lo32.
// gkey triple-buffered; slot (g+1)%3 reset in step g (race-free). Exact
// np.argmax first-occurrence semantics incl. ties.
// In-loop global stores REMOVED: t0 records fi into s_fi[] (LDS); a parallel
// epilogue (thread t <-> group t) writes out_fps/out_center once. Avoids the
// per-step vmcnt(0) drain of t0's global stores at the barrier.
// NOTE (round-1 post-mortem): do NOT move the cross-wave reduce post-barrier
// (slots+tree) — atomic is pre-barrier and hidden by skew; the tree sits on
// every wave's post-barrier critical path (+165 cyc/step measured).
// ---------------------------------------------------------------------------
__global__ __launch_bounds__(FPS_THREADS, 2)
void fps_kernel(const float* __restrict__ xyz,
                float* __restrict__ out_center,
                float* __restrict__ out_fps)
{
#pragma clang fp contract(off)
    extern __shared__ float sxyz[];                        // [24576]
    __shared__ unsigned long long gkey[3];
    __shared__ int s_fi[NGROUP];

    const int b    = blockIdx.x;
    const int t    = threadIdx.x;
    const int lane = t & 63;
    const float* bp = xyz + (size_t)b * NPTS * 3;
    const float4* bp4 = reinterpret_cast<const float4*>(bp);
    float4* s4 = reinterpret_cast<float4*>(sxyz);

    // contiguous ownership: thread t owns points 16t..16t+15 (12 float4).
    // Direct float4 -> v2 placement (no f[48] intermediate); mapping identical
    // to the verified version: px2[j] = {f[6j+0], f[6j+3]}, etc.
    v2f px2[8], py2[8], pz2[8], dist2[8];
    #pragma unroll
    for (int j = 0; j < 8; ++j) dist2[j] = (v2f){INFINITY, INFINITY};
    #pragma unroll
    for (int q = 0; q < 12; ++q) {
        float4 v = bp4[t * 12 + q];
        s4[t * 12 + q] = v;
        const float vv[4] = {v.x, v.y, v.z, v.w};
        #pragma unroll
        for (int e = 0; e < 4; ++e) {
            const int n  = q * 4 + e;      // 0..47, compile-time
            const int j2 = n / 3;          // point within thread (0..15)
            const int c  = n % 3;          // coord
            const int h  = j2 >> 1;        // v2 slot
            const float val = vv[e];
            if (c == 0) { if (j2 & 1) px2[h].y = val; else px2[h].x = val; }
            else if (c == 1) { if (j2 & 1) py2[h].y = val; else py2[h].x = val; }
            else { if (j2 & 1) pz2[h].y = val; else pz2[h].x = val; }
        }
    }
    if (t == 0) { gkey[0] = 0; gkey[1] = 0; gkey[2] = 0; s_fi[0] = 0; }
    __syncthreads();   // sxyz + gkey visible

    int last = 0;
    for (int g = 1; g < NGROUP; ++g) {
        const int slot = g % 3;
        const int nxt  = (g + 1) % 3;
        float lx = sxyz[last*3 + 0];     // broadcast LDS reads
        float ly = sxyz[last*3 + 1];
        float lz = sxyz[last*3 + 2];

        // packed dist update: per element (dx*dx + dy*dy) + dz*dz, then min
        #pragma unroll
        for (int j = 0; j < 8; ++j) {
            v2f dx = px2[j] - lx;
            v2f dy = py2[j] - ly;
            v2f dz = pz2[j] - lz;
            v2f t1 = dx * dx;
            v2f t2 = dy * dy;
            v2f t3 = dz * dz;
            v2f s  = t1 + t2;
            v2f d  = s + t3;
            dist2[j] = __builtin_elementwise_min(dist2[j], d);
        }
        // per-thread max (exact, order-free)
        v2f mm0 = __builtin_elementwise_max(dist2[0], dist2[1]);
        v2f mm1 = __builtin_elementwise_max(dist2[2], dist2[3]);
        v2f mm2 = __builtin_elementwise_max(dist2[4], dist2[5]);
        v2f mm3 = __builtin_elementwise_max(dist2[6], dist2[7]);
        v2f mma = __builtin_elementwise_max(mm0, mm1);
        v2f mmb = __builtin_elementwise_max(mm2, mm3);
        v2f mmc = __builtin_elementwise_max(mma, mmb);
        float m_t = fmaxf(mmc.x, mmc.y);

        // wave max via DPP -> wmax (uniform, sgpr)
        float m = m_t;
        m = dpp_max_f32<0xB1>(m);     // quad_perm xor1
        m = dpp_max_f32<0x4E>(m);     // quad_perm xor2
        m = dpp_max_f32<0x141>(m);    // row_half_mirror
        m = dpp_max_f32<0x140>(m);    // row_mirror
        m = dpp_max_f32<0x142>(m);    // row_bcast15
        m = dpp_max_f32<0x143>(m);    // row_bcast31
        float wmax = __int_as_float(__builtin_amdgcn_readlane(__float_as_int(m), 63));

        // lowest candidate lane (contiguous ownership => lane order = idx order)
        unsigned long long mask = __ballot(m_t == wmax);
        int l = __ffsll((long long)mask) - 1;

        // lowest j with d[j]==wmax: pair candidates + 3-level min tree
        // (same first-occurrence semantics as the 16-deep chain, depth ~6)
        unsigned cand[8];
        #pragma unroll
        for (int p = 0; p < 8; ++p) {
            unsigned c = 0xFFFFFFFFu;
            c = (dist2[p].y == wmax) ? (unsigned)(2*p + 1) : c;
            c = (dist2[p].x == wmax) ? (unsigned)(2*p)     : c;   // x preferred
            cand[p] = c;
        }
        unsigned q0 = cand[0] < cand[1] ? cand[0] : cand[1];
        unsigned q1 = cand[2] < cand[3] ? cand[2] : cand[3];
        unsigned q2 = cand[4] < cand[5] ? cand[4] : cand[5];
        unsigned q3 = cand[6] < cand[7] ? cand[6] : cand[7];
        unsigned qa = q0 < q1 ? q0 : q1;
        unsigned qb = q2 < q3 ? q2 : q3;
        unsigned lj = qa < qb ? qa : qb;       // <16 on candidate lanes
        unsigned idx = ((unsigned)t << 4) | lj;
        unsigned widx = (unsigned)__builtin_amdgcn_readlane((int)idx, l);

        if (lane == 63) {
            unsigned long long key =
                (((unsigned long long)__float_as_uint(wmax)) << 32) | (unsigned)~widx;
            atomicMax(&gkey[slot], key);
            if (t == 63) gkey[nxt] = 0;   // reset slot for step g+1 (pre-barrier)
        }
        __syncthreads();                  // the ONE barrier

        unsigned long long kq = gkey[slot];   // broadcast b64 read
        int fi = (int)(~(unsigned)kq);
        last = fi;
        if (t == 0) s_fi[g] = fi;             // LDS only; no global stores in loop
    }

    // epilogue: thread t <-> group t (512 threads, 512 groups)
    __syncthreads();                          // s_fi[511] visible
    {
        const int g  = t;
        const int fi = s_fi[g];
        out_fps[(size_t)b * NGROUP + g] = (float)fi;
        const size_t o = ((size_t)(b * NGROUP + g)) * 3;
        out_center[o + 0] = sxyz[fi*3 + 0];
        out_center[o + 1] = sxyz[fi*3 + 1];
        out_center[o + 2] = sxyz[fi*3 + 2];
    }
}

// ---------------------------------------------------------------------------
// kNN: verbatim round-0 version (known 113 µs). One wave/group. Per lane:
// 128 pts (3 float4 / 4 pts, packed f32 dist), per-lane top-4 as sorted u32
// keys (distbits&~0x1FFF | idx13), then 32 rounds of wave min+pop.
// Post-mortems: LDS-resident (r1) and CPW=4 load-amortized (r2) BOTH lost —
// knn is occupancy/latency-sensitive, not BW-bound; max wave count wins.
// ---------------------------------------------------------------------------
__global__ __launch_bounds__(256)
void knn_kernel(const float* __restrict__ xyz,
                const float* __restrict__ center,
                float* __restrict__ out_nbhd)
{
    const int lane = threadIdx.x & 63;
    const int gid  = blockIdx.x * 4 + (threadIdx.x >> 6);   // 0..16383
    const int b    = gid >> 9;
    const float* bp = xyz + (size_t)b * NPTS * 3;
    const float4* bp4 = reinterpret_cast<const float4*>(bp);

    const float cx = center[(size_t)gid*3+0];
    const float cy = center[(size_t)gid*3+1];
    const float cz = center[(size_t)gid*3+2];

    unsigned kl[4];
    #pragma unroll
    for (int k = 0; k < 4; ++k) kl[k] = 0xFFFFFFFFu;

    for (int c = 0; c < 32; ++c) {
        int f4 = c * 192 + lane * 3;
        float4 a  = bp4[f4+0];
        float4 bq = bp4[f4+1];
        float4 cq = bp4[f4+2];
        unsigned p0 = (unsigned)(c * 256 + lane * 4);
        v2f xA = (v2f){a.x,  a.w},  yA = (v2f){a.y,  bq.x}, zA = (v2f){a.z,  bq.y};
        v2f xB = (v2f){bq.z, cq.y}, yB = (v2f){bq.w, cq.z}, zB = (v2f){cq.x, cq.w};
        v2f dxA = xA - cx, dyA = yA - cy, dzA = zA - cz;
        v2f dxB = xB - cx, dyB = yB - cy, dzB = zB - cz;
        v2f dA = dxA*dxA + dyA*dyA + dzA*dzA;
        v2f dB = dxB*dxB + dyB*dyB + dzB*dzB;
        float ds[4] = {dA.x, dA.y, dB.x, dB.y};
        #pragma unroll
        for (int k = 0; k < 4; ++k) {
            unsigned key = (__float_as_uint(ds[k]) & 0xFFFFE000u) | (p0 + k);
            if (key < kl[3]) {
                kl[3] = key;
                #pragma unroll
                for (int q = 3; q > 0; --q) {
                    if (kl[q] < kl[q-1]) {
                        unsigned tk = kl[q]; kl[q] = kl[q-1]; kl[q-1] = tk;
                    }
                }
            }
        }
    }

    int keep = 0;
    #pragma unroll 1
    for (int r = 0; r < MSIZE; ++r) {
        unsigned k = kl[0];
        k = dpp_min_u32_full<0xB1>(k);     // xor1
        k = dpp_min_u32_full<0x4E>(k);     // xor2
        k = dpp_min_u32_full<0x141>(k);    // half mirror
        k = dpp_min_u32_full<0x140>(k);    // mirror -> rows of 16 uniform
        {
            unsigned o = __shfl_xor(k, 16);
            k = o < k ? o : k;
            o = __shfl_xor(k, 32);
            k = o < k ? o : k;
        }
        if (lane == r) keep = (int)(k & 0x1FFFu);
        if (kl[0] == k) {                   // unique (idx embedded)
            kl[0] = kl[1]; kl[1] = kl[2]; kl[2] = kl[3];
            kl[3] = 0xFFFFFFFFu;
        }
    }

    if (lane < MSIZE) {
        size_t o = ((size_t)gid * MSIZE + lane) * 3;
        float x = bp[keep*3+0], y = bp[keep*3+1], z = bp[keep*3+2];
        out_nbhd[o+0] = x - cx;
        out_nbhd[o+1] = y - cy;
        out_nbhd[o+2] = z - cz;
    }
}

// ---------------------------------------------------------------------------
extern "C" void kernel_launch(void* const* d_in, const int* in_sizes, int n_in,
                              void* d_out, int out_size, void* d_ws, size_t ws_size,
                              hipStream_t stream)
{
    const float* xyz = (const float*)d_in[0];
    float* out        = (float*)d_out;
    float* out_nbhd   = out;                                    // 32*512*32*3
    float* out_center = out + (size_t)BATCH*NGROUP*MSIZE*3;     // 32*512*3
    float* out_fps    = out_center + (size_t)BATCH*NGROUP*3;    // 32*512

    hipFuncSetAttribute(reinterpret_cast<const void*>(fps_kernel),
                        hipFuncAttributeMaxDynamicSharedMemorySize,
                        DYN_LDS_BYTES);

    fps_kernel<<<dim3(BATCH), dim3(FPS_THREADS), DYN_LDS_BYTES, stream>>>(xyz, out_center, out_fps);
    knn_kernel<<<dim3(BATCH*NGROUP/4), dim3(256), 0, stream>>>(xyz, out_center, out_nbhd);
}